// Round 1
// baseline (32.927 us; speedup 1.0000x reference)
//
#include <hip/hip_runtime.h>
#include <hip/hip_bf16.h>
#include <math.h>

#define NN 384   // 2*B
#define BB 192   // B
#define DD 128   // feature dim

// TEMP = 2.0 -> s = -dist * 0.5
// TAU = 1.0, POS_W = 0.1, NEG_W = 1.0, SOFT = true

__global__ __launch_bounds__(NN) void contrastive_loss_kernel(
    const float* __restrict__ emb,   // [192, 2, 128]
    const float* __restrict__ tgt,   // [192, 1]
    float* __restrict__ out)         // [1]
{
    const int i = blockIdx.x;   // row
    const int t = threadIdx.x;  // column j (and positive index p)

    __shared__ float zi[DD];
    __shared__ float a_sh[NN];   // |y_i - y_j|
    __shared__ float w_sh[NN];   // e_j * dw_j        (not-closer weight 1.0)
    __shared__ float c1_sh[NN];  // same ? 0.1*w : 0  (closer weight)
    __shared__ float partials[NN / 64];

    // z[r] = embeddings[r % 192, r / 192, :]
    const int ioff = (i < BB) ? i * 2 * DD : ((i - BB) * 2 + 1) * DD;
    if (t < DD) zi[t] = emb[ioff + t];
    __syncthreads();

    // s_t = -||z_i - z_t|| / TEMP   (row max is exactly 0 -> e = exp(s))
    const int joff = (t < BB) ? t * 2 * DD : ((t - BB) * 2 + 1) * DD;
    const float4* zj4 = reinterpret_cast<const float4*>(emb + joff);
    float sq = 0.f;
#pragma unroll
    for (int d4 = 0; d4 < DD / 4; ++d4) {
        float4 v = zj4[d4];
        float d0 = zi[d4 * 4 + 0] - v.x;
        float d1 = zi[d4 * 4 + 1] - v.y;
        float d2 = zi[d4 * 4 + 2] - v.z;
        float d3 = zi[d4 * 4 + 3] - v.w;
        sq += d0 * d0 + d1 * d1 + d2 * d2 + d3 * d3;
    }
    const float dist = (sq > 0.f) ? sqrtf(sq) : 0.f;
    const float s = -dist * 0.5f;  // / TEMP

    const float yi = tgt[(i < BB) ? i : i - BB];
    const float yj = tgt[(t < BB) ? t : t - BB];
    const float sg = yi - yj;             // signed[i][j], bitwise == reference
    const float a = fabsf(sg);
    const bool same = sg < 0.f;
    const float dwt = 1.f / (1.f + expf(-a));  // sigmoid(TAU * a)
    float w = expf(s) * dwt;
    float c1 = same ? 0.1f * w : 0.f;
    if (t == i) { w = 0.f; c1 = 0.f; }  // exclude diagonal from all sums
    a_sh[t] = a;
    w_sh[t] = w;
    c1_sh[t] = c1;
    __syncthreads();

    // denom[p] = sum_j (a_j < a_p) ? c1_j : w_j   -- uniform j => LDS broadcast
    const float ap = a;
    float denom = 0.f;
#pragma unroll 8
    for (int j = 0; j < NN; ++j) {
        denom += (a_sh[j] < ap) ? c1_sh[j] : w_sh[j];
    }

    float contrib = (t == i) ? 0.f : (s - logf(denom));

    // block reduction (6 waves)
    const int lane = t & 63, wid = t >> 6;
    for (int off = 32; off > 0; off >>= 1)
        contrib += __shfl_down(contrib, off);
    if (lane == 0) partials[wid] = contrib;
    __syncthreads();
    if (t == 0) {
        float ssum = 0.f;
#pragma unroll
        for (int k = 0; k < NN / 64; ++k) ssum += partials[k];
        atomicAdd(out, -ssum * (1.f / (NN * (NN - 1.f))));
    }
}

extern "C" void kernel_launch(void* const* d_in, const int* in_sizes, int n_in,
                              void* d_out, int out_size, void* d_ws, size_t ws_size,
                              hipStream_t stream) {
    const float* emb = (const float*)d_in[0];  // 192*2*128 f32
    const float* tgt = (const float*)d_in[1];  // 192 f32
    float* out = (float*)d_out;                // 1 f32

    hipMemsetAsync(out, 0, sizeof(float), stream);
    contrastive_loss_kernel<<<NN, NN, 0, stream>>>(emb, tgt, out);
}

// Round 2
// 26.928 us; speedup vs baseline: 1.2228x; 1.2228x over previous
//
#include <hip/hip_runtime.h>
#include <hip/hip_bf16.h>
#include <math.h>

#define NN 384   // 2*B
#define BB 192   // B
#define DD 128   // feature dim

// TEMP=2.0 -> s = -dist*0.5 ; TAU=1.0 ; POS_W=0.1 ; NEG_W=1.0 ; SOFT=true
//
// denom[i,p] = sum_j (a_j<a_p ? c1_j : w_j)
//            = Wtot_i + sum_{j: a_j<a_p} (c1_j - w_j)
// and {j : |y_i-y_j| < a_p} is a contiguous interval in y-sorted order.

// ---- kernel 1: global rank of each y (row-independent), sorted y, zero out ----
__global__ __launch_bounds__(64) void rank_kernel(const float* __restrict__ tgt,
                                                  float* __restrict__ ys,
                                                  int* __restrict__ rnk,
                                                  float* __restrict__ out) {
    const int r = blockIdx.x;       // element 0..383
    const int lane = threadIdx.x;   // 0..63
    const float yr = tgt[(r < BB) ? r : r - BB];
    int cnt = 0;
    for (int q = lane; q < NN; q += 64) {
        const float yq = tgt[(q < BB) ? q : q - BB];
        cnt += (yq < yr || (yq == yr && q < r)) ? 1 : 0;  // stable rank, distinct
    }
    for (int off = 32; off; off >>= 1) cnt += __shfl_down(cnt, off);
    if (lane == 0) {
        ys[cnt] = yr;    // sorted y (all ranks distinct -> fully written)
        rnk[r] = cnt;
        if (r == 0) out[0] = 0.f;   // replaces memset node
    }
}

// ---- kernel 2: one block per row i ----
__global__ __launch_bounds__(NN) void loss_kernel(const float* __restrict__ emb,
                                                  const float* __restrict__ tgt,
                                                  const float* __restrict__ ys_g,
                                                  const int* __restrict__ rnk_g,
                                                  float* __restrict__ out) {
    const int i = blockIdx.x;
    const int t = threadIdx.x;

    __shared__ float zi[DD];
    __shared__ float ys[NN];
    __shared__ float dsort[NN];
    __shared__ float P[NN + 1];        // exclusive prefix of dsort
    __shared__ float part[NN / 64];    // wave partials (reused)
    __shared__ float wtot_sh;

    const int ioff = (i < BB) ? i * 2 * DD : ((i - BB) * 2 + 1) * DD;
    if (t < DD) zi[t] = emb[ioff + t];
    ys[t] = ys_g[t];
    const int rk = rnk_g[t];
    __syncthreads();

    // s_t = -||z_i - z_t|| / 2  (row max is exactly 0)
    const int joff = (t < BB) ? t * 2 * DD : ((t - BB) * 2 + 1) * DD;
    const float4* zj4 = reinterpret_cast<const float4*>(emb + joff);
    const float4* zi4 = reinterpret_cast<const float4*>(zi);
    float sq = 0.f;
#pragma unroll
    for (int d4 = 0; d4 < DD / 4; ++d4) {
        float4 v = zj4[d4];
        float4 u = zi4[d4];
        float d0 = u.x - v.x, d1 = u.y - v.y, d2 = u.z - v.z, d3 = u.w - v.w;
        sq += d0 * d0 + d1 * d1 + d2 * d2 + d3 * d3;
    }
    const float dist = (sq > 0.f) ? sqrtf(sq) : 0.f;
    const float s = -dist * 0.5f;

    const float yi = tgt[(i < BB) ? i : i - BB];
    const float yj = tgt[(t < BB) ? t : t - BB];
    const float sg = yi - yj;            // bitwise == reference signed[i][t]
    const float ap = fabsf(sg);
    const float dwt = 1.f / (1.f + expf(-ap));   // sigmoid(TAU*a)
    float w = expf(s) * dwt;
    float dval = (sg < 0.f) ? (0.1f * w - w) : (0.f - w);  // c1 - w
    if (t == i) { w = 0.f; dval = 0.f; }  // exclude diagonal everywhere
    dsort[rk] = dval;                     // scatter into sorted order
    __syncthreads();

    // inclusive shuffle-scan of dsort (element t), plus block sum of w
    float v = dsort[t];
    const int lane = t & 63, wid = t >> 6;
    for (int off = 1; off < 64; off <<= 1) {
        float o = __shfl_up(v, off);
        if (lane >= off) v += o;
    }
    __shared__ float wavesum[NN / 64];
    if (lane == 63) wavesum[wid] = v;
    float wv = w;
    for (int off = 32; off; off >>= 1) wv += __shfl_down(wv, off);
    if (lane == 0) part[wid] = wv;
    __syncthreads();
    float base = 0.f;
    for (int k = 0; k < wid; ++k) base += wavesum[k];
    P[t + 1] = base + v;
    if (t == 0) {
        P[0] = 0.f;
        float W = 0.f;
        for (int k = 0; k < NN / 64; ++k) W += part[k];
        wtot_sh = W;
    }
    __syncthreads();
    const float Wtot = wtot_sh;

    // interval [lo,hi) of sorted positions with |yi - ys[m]| < ap
    // pL(m) = (yi - ys[m] < ap): monotone F->T ; pR(m) = (ys[m] - yi < ap): T->F
    int l = 0, r = NN;
    while (l < r) { int m = (l + r) >> 1; if (yi - ys[m] < ap) r = m; else l = m + 1; }
    const int lo = l;
    l = 0; r = NN;
    while (l < r) { int m = (l + r) >> 1; if (!(ys[m] - yi < ap)) r = m; else l = m + 1; }
    const int hi = l;

    float denom = Wtot;
    if (hi > lo) denom += P[hi] - P[lo];

    float contrib = (t == i) ? 0.f : (s - logf(denom));

    for (int off = 32; off; off >>= 1) contrib += __shfl_down(contrib, off);
    if (lane == 0) part[wid] = contrib;
    __syncthreads();
    if (t == 0) {
        float ssum = 0.f;
        for (int k = 0; k < NN / 64; ++k) ssum += part[k];
        atomicAdd(out, -ssum * (1.f / (NN * (NN - 1.f))));
    }
}

extern "C" void kernel_launch(void* const* d_in, const int* in_sizes, int n_in,
                              void* d_out, int out_size, void* d_ws, size_t ws_size,
                              hipStream_t stream) {
    const float* emb = (const float*)d_in[0];  // [192,2,128] f32
    const float* tgt = (const float*)d_in[1];  // [192,1] f32
    float* out = (float*)d_out;

    float* ys = (float*)d_ws;
    int* rnk = (int*)((char*)d_ws + NN * sizeof(float));

    rank_kernel<<<NN, 64, 0, stream>>>(tgt, ys, rnk, out);
    loss_kernel<<<NN, NN, 0, stream>>>(emb, tgt, ys, rnk, out);
}